// Round 1
// baseline (1311.135 us; speedup 1.0000x reference)
//
#include <hip/hip_runtime.h>

#define N_NODES  100000
#define N_EDGES  6400000
#define N_GRAPHS 64

// Workspace layout (floats):
//  deg   [N]      degree (init 1.0 for self-loop)
//  dinv  [N]      deg^-1/2
//  acc1  [N]      sum over in-edges of dinv[src]*x[src]
//  accz  [N]      sum over in-edges of dinv[src]
//  y1    [N]      (A_hat x)_i
//  z     [N]      (A_hat 1)_i
//  acc2  [N]      sum over in-edges of dinv[src]*y1[src]
//  gacc  [192]    per-graph {sum_y[64], sum_z[64], count[64]}
//  flag  (int)    index element stride: 1 = int32 layout, 2 = int64 layout

__global__ void detect_kernel(const int* ei, int* flag) {
    if (blockIdx.x == 0 && threadIdx.x == 0) {
        // If indices are int64 (values < 100000, non-negative), every hi word is 0.
        int allzero = 1;
        for (int k = 0; k < 16; ++k)
            if (ei[2 * k + 1] != 0) allzero = 0;
        *flag = allzero ? 2 : 1;
    }
}

__global__ void init_kernel(float* deg, float* acc1, float* accz, float* acc2, float* gacc) {
    int i = blockIdx.x * blockDim.x + threadIdx.x;
    if (i < N_NODES) {
        deg[i]  = 1.0f;   // self-loop
        acc1[i] = 0.0f;
        accz[i] = 0.0f;
        acc2[i] = 0.0f;
    }
    if (i < 3 * N_GRAPHS) gacc[i] = 0.0f;
}

__global__ void deg_kernel(const int* ei, const int* flag, float* deg) {
    const int stride = *flag;
    const int* dstp = ei + (size_t)N_EDGES * stride;
    int tid = blockIdx.x * blockDim.x + threadIdx.x;
    int nth = gridDim.x * blockDim.x;
    for (int e = tid; e < N_EDGES; e += nth)
        atomicAdd(&deg[dstp[(size_t)e * stride]], 1.0f);
}

__global__ void dinv_kernel(const float* deg, float* dinv) {
    int i = blockIdx.x * blockDim.x + threadIdx.x;
    if (i < N_NODES) dinv[i] = rsqrtf(deg[i]);   // deg >= 1 always
}

__global__ void edge1_kernel(const int* ei, const int* flag, const float* x,
                             const float* dinv, float* acc1, float* accz) {
    const int stride = *flag;
    const int* srcp = ei;
    const int* dstp = ei + (size_t)N_EDGES * stride;
    int tid = blockIdx.x * blockDim.x + threadIdx.x;
    int nth = gridDim.x * blockDim.x;
    for (int e = tid; e < N_EDGES; e += nth) {
        int s = srcp[(size_t)e * stride];
        int d = dstp[(size_t)e * stride];
        float v = dinv[s];
        atomicAdd(&acc1[d], v * x[s]);
        atomicAdd(&accz[d], v);
    }
}

__global__ void node1_kernel(const float* x, const float* dinv,
                             const float* acc1, const float* accz,
                             float* y1, float* z) {
    int i = blockIdx.x * blockDim.x + threadIdx.x;
    if (i < N_NODES) {
        float di = dinv[i];
        y1[i] = di * (acc1[i] + di * x[i]);   // A_hat x  (self-loop term dinv^2 * x)
        z[i]  = di * (accz[i] + di);          // A_hat 1
    }
}

__global__ void edge2_kernel(const int* ei, const int* flag,
                             const float* dinv, const float* y1, float* acc2) {
    const int stride = *flag;
    const int* srcp = ei;
    const int* dstp = ei + (size_t)N_EDGES * stride;
    int tid = blockIdx.x * blockDim.x + threadIdx.x;
    int nth = gridDim.x * blockDim.x;
    for (int e = tid; e < N_EDGES; e += nth) {
        int s = srcp[(size_t)e * stride];
        int d = dstp[(size_t)e * stride];
        atomicAdd(&acc2[d], dinv[s] * y1[s]);
    }
}

__global__ void pool_kernel(const int* batch, const int* flag, const float* dinv,
                            const float* y1, const float* z, const float* acc2,
                            float* gacc) {
    __shared__ float s[3 * N_GRAPHS];
    int t = threadIdx.x;
    for (int i = t; i < 3 * N_GRAPHS; i += blockDim.x) s[i] = 0.0f;
    __syncthreads();
    const int stride = *flag;
    int tid = blockIdx.x * blockDim.x + t;
    int nth = gridDim.x * blockDim.x;
    for (int i = tid; i < N_NODES; i += nth) {
        float di = dinv[i];
        float y  = di * (acc2[i] + di * y1[i]);   // A_hat^2 x
        int g = batch[(size_t)i * stride];
        atomicAdd(&s[g], y);
        atomicAdd(&s[N_GRAPHS + g], z[i]);
        atomicAdd(&s[2 * N_GRAPHS + g], 1.0f);
    }
    __syncthreads();
    for (int i = t; i < 3 * N_GRAPHS; i += blockDim.x)
        if (s[i] != 0.0f) atomicAdd(&gacc[i], s[i]);
}

__global__ void final_kernel(const float* W1, const float* b1, const float* W2,
                             const float* b2, const float* gacc, float* out) {
    int g = threadIdx.x;
    if (g >= N_GRAPHS) return;
    // w[k] = sum_j W1[j] * W2[j][k];  c[k] = sum_j b1[j] * W2[j][k]
    float w0 = 0.f, w1 = 0.f, c0 = 0.f, c1 = 0.f;
    for (int j = 0; j < 16; ++j) {
        float a = W2[2 * j], b = W2[2 * j + 1];
        w0 += W1[j] * a;  w1 += W1[j] * b;
        c0 += b1[j] * a;  c1 += b1[j] * b;
    }
    float sy  = gacc[g];
    float sz  = gacc[N_GRAPHS + g];
    float cnt = gacc[2 * N_GRAPHS + g];
    float inv = 1.0f / fmaxf(cnt, 1.0f);
    // out = (sum_y * w + sum_z * c + cnt * b2) / max(cnt, 1)   (exact match to ref, incl. cnt==0)
    out[2 * g + 0] = (sy * w0 + sz * c0 + cnt * b2[0]) * inv;
    out[2 * g + 1] = (sy * w1 + sz * c1 + cnt * b2[1]) * inv;
}

extern "C" void kernel_launch(void* const* d_in, const int* in_sizes, int n_in,
                              void* d_out, int out_size, void* d_ws, size_t ws_size,
                              hipStream_t stream) {
    const float* x     = (const float*)d_in[0];
    const int*   ei    = (const int*)d_in[1];
    const int*   batch = (const int*)d_in[2];
    const float* W1    = (const float*)d_in[3];
    const float* b1    = (const float*)d_in[4];
    const float* W2    = (const float*)d_in[5];
    const float* b2    = (const float*)d_in[6];
    float* out = (float*)d_out;

    float* f    = (float*)d_ws;
    float* deg  = f + 0 * N_NODES;
    float* dinv = f + 1 * N_NODES;
    float* acc1 = f + 2 * N_NODES;
    float* accz = f + 3 * N_NODES;
    float* y1   = f + 4 * N_NODES;
    float* z    = f + 5 * N_NODES;
    float* acc2 = f + 6 * N_NODES;
    float* gacc = f + 7 * N_NODES;
    int*   flag = (int*)(f + 7 * N_NODES + 3 * N_GRAPHS);

    const int BS = 256;
    const int nodeGrid = (N_NODES + BS - 1) / BS;
    const int edgeGrid = 2048;

    detect_kernel<<<1, 64, 0, stream>>>(ei, flag);
    init_kernel<<<nodeGrid, BS, 0, stream>>>(deg, acc1, accz, acc2, gacc);
    deg_kernel<<<edgeGrid, BS, 0, stream>>>(ei, flag, deg);
    dinv_kernel<<<nodeGrid, BS, 0, stream>>>(deg, dinv);
    edge1_kernel<<<edgeGrid, BS, 0, stream>>>(ei, flag, x, dinv, acc1, accz);
    node1_kernel<<<nodeGrid, BS, 0, stream>>>(x, dinv, acc1, accz, y1, z);
    edge2_kernel<<<edgeGrid, BS, 0, stream>>>(ei, flag, dinv, y1, acc2);
    pool_kernel<<<nodeGrid, BS, 0, stream>>>(batch, flag, dinv, y1, z, acc2, gacc);
    final_kernel<<<1, 64, 0, stream>>>(W1, b1, W2, b2, gacc, out);
}

// Round 2
// 1271.777 us; speedup vs baseline: 1.0309x; 1.0309x over previous
//
#include <hip/hip_runtime.h>

#define N_NODES  100000
#define N_EDGES  6400000
#define N_GRAPHS 64

// Scopes for __hip_atomic_fetch_add
#define SC_WG __HIP_MEMORY_SCOPE_WORKGROUP
#define SC_AG __HIP_MEMORY_SCOPE_AGENT

// Physical XCD id of this wave (0..7 on MI355X). Wave-uniform; a wave never
// migrates XCDs, so using it to pick an XCD-private accumulator copy is safe.
__device__ __forceinline__ unsigned xcc_id() {
    unsigned x;
    asm("s_getreg_b32 %0, hwreg(HW_REG_XCC_ID)" : "=s"(x));
    return x & 7u;
}

template <bool MULTI>
__device__ __forceinline__ void acc_add(float* base, int copyStrideElems, int idx, float v) {
    // MULTI: per-XCD copy + workgroup-scope atomic -> executes in XCD-local L2.
    // else : single copy + agent-scope atomic (coherent fallback).
    if (MULTI) {
        float* p = base + (size_t)xcc_id() * copyStrideElems + idx;
        (void)__hip_atomic_fetch_add(p, v, __ATOMIC_RELAXED, SC_WG);
    } else {
        (void)__hip_atomic_fetch_add(base + idx, v, __ATOMIC_RELAXED, SC_AG);
    }
}

__global__ void detect_kernel(const int* ei, int* flag) {
    if (blockIdx.x == 0 && threadIdx.x == 0) {
        // int64 indices (values < 100000, non-negative) => every hi word is 0.
        int allzero = 1;
        for (int k = 0; k < 16; ++k)
            if (ei[2 * k + 1] != 0) allzero = 0;
        *flag = allzero ? 2 : 1;
    }
}

__global__ void zero_kernel(float* p, int n) {
    int tid = blockIdx.x * blockDim.x + threadIdx.x;
    int nth = gridDim.x * blockDim.x;
    for (int i = tid; i < n; i += nth) p[i] = 0.0f;
}

template <bool MULTI>
__global__ void deg_kernel(const int* ei, const int* flag, float* deg8) {
    const int stride = *flag;
    const int* dstp = ei + (size_t)N_EDGES * stride;
    int tid = blockIdx.x * blockDim.x + threadIdx.x;
    int nth = gridDim.x * blockDim.x;
    for (int e = tid; e < N_EDGES; e += nth)
        acc_add<MULTI>(deg8, N_NODES, dstp[(size_t)e * stride], 1.0f);
}

__global__ void dinv_kernel(const float* deg8, int ncopy, float* dinv) {
    int i = blockIdx.x * blockDim.x + threadIdx.x;
    if (i >= N_NODES) return;
    float d = 1.0f;  // self-loop
    for (int c = 0; c < ncopy; ++c) d += deg8[(size_t)c * N_NODES + i];
    dinv[i] = rsqrtf(d);
}

template <bool MULTI>
__global__ void edge1_kernel(const int* ei, const int* flag, const float* x,
                             const float* dinv, float* acc1, float* accz) {
    const int stride = *flag;
    const int* srcp = ei;
    const int* dstp = ei + (size_t)N_EDGES * stride;
    int tid = blockIdx.x * blockDim.x + threadIdx.x;
    int nth = gridDim.x * blockDim.x;
    for (int e = tid; e < N_EDGES; e += nth) {
        int s = srcp[(size_t)e * stride];
        int d = dstp[(size_t)e * stride];
        float v = dinv[s];
        acc_add<MULTI>(acc1, N_NODES, d, v * x[s]);
        acc_add<MULTI>(accz, N_NODES, d, v);
    }
}

__global__ void node1_kernel(const float* x, const float* dinv,
                             const float* acc1, const float* accz, int ncopy,
                             float* y1, float* z) {
    int i = blockIdx.x * blockDim.x + threadIdx.x;
    if (i >= N_NODES) return;
    float a1 = 0.0f, az = 0.0f;
    for (int c = 0; c < ncopy; ++c) {
        a1 += acc1[(size_t)c * N_NODES + i];
        az += accz[(size_t)c * N_NODES + i];
    }
    float di = dinv[i];
    y1[i] = di * (a1 + di * x[i]);   // (A_hat x)_i  (self-loop term dinv^2 * x)
    z[i]  = di * (az + di);          // (A_hat 1)_i
}

template <bool MULTI>
__global__ void edge2_kernel(const int* ei, const int* flag,
                             const float* dinv, const float* y1, float* acc2) {
    const int stride = *flag;
    const int* srcp = ei;
    const int* dstp = ei + (size_t)N_EDGES * stride;
    int tid = blockIdx.x * blockDim.x + threadIdx.x;
    int nth = gridDim.x * blockDim.x;
    for (int e = tid; e < N_EDGES; e += nth) {
        int s = srcp[(size_t)e * stride];
        int d = dstp[(size_t)e * stride];
        acc_add<MULTI>(acc2, N_NODES, d, dinv[s] * y1[s]);
    }
}

template <bool MULTI>
__global__ void pool_kernel(const int* batch, const int* flag, const float* dinv,
                            const float* y1, const float* z, const float* acc2,
                            int ncopy, float* gacc8) {
    __shared__ float s[3 * N_GRAPHS];
    int t = threadIdx.x;
    for (int i = t; i < 3 * N_GRAPHS; i += blockDim.x) s[i] = 0.0f;
    __syncthreads();
    const int stride = *flag;
    int tid = blockIdx.x * blockDim.x + t;
    int nth = gridDim.x * blockDim.x;
    for (int i = tid; i < N_NODES; i += nth) {
        float a2 = 0.0f;
        for (int c = 0; c < ncopy; ++c) a2 += acc2[(size_t)c * N_NODES + i];
        float di = dinv[i];
        float y  = di * (a2 + di * y1[i]);     // (A_hat^2 x)_i
        int g = batch[(size_t)i * stride];
        atomicAdd(&s[g], y);
        atomicAdd(&s[N_GRAPHS + g], z[i]);
        atomicAdd(&s[2 * N_GRAPHS + g], 1.0f);
    }
    __syncthreads();
    for (int i = t; i < 3 * N_GRAPHS; i += blockDim.x)
        if (s[i] != 0.0f) acc_add<MULTI>(gacc8, 3 * N_GRAPHS, i, s[i]);
}

__global__ void final_kernel(const float* W1, const float* b1, const float* W2,
                             const float* b2, const float* gacc8, int ncopy,
                             float* out) {
    int g = threadIdx.x;
    if (g >= N_GRAPHS) return;
    float w0 = 0.f, w1 = 0.f, c0 = 0.f, c1 = 0.f;
    for (int j = 0; j < 16; ++j) {
        float a = W2[2 * j], b = W2[2 * j + 1];
        w0 += W1[j] * a;  w1 += W1[j] * b;
        c0 += b1[j] * a;  c1 += b1[j] * b;
    }
    float sy = 0.f, sz = 0.f, cnt = 0.f;
    for (int c = 0; c < ncopy; ++c) {
        const float* gc = gacc8 + (size_t)c * 3 * N_GRAPHS;
        sy  += gc[g];
        sz  += gc[N_GRAPHS + g];
        cnt += gc[2 * N_GRAPHS + g];
    }
    float inv = 1.0f / fmaxf(cnt, 1.0f);
    out[2 * g + 0] = (sy * w0 + sz * c0 + cnt * b2[0]) * inv;
    out[2 * g + 1] = (sy * w1 + sz * c1 + cnt * b2[1]) * inv;
}

extern "C" void kernel_launch(void* const* d_in, const int* in_sizes, int n_in,
                              void* d_out, int out_size, void* d_ws, size_t ws_size,
                              hipStream_t stream) {
    const float* x     = (const float*)d_in[0];
    const int*   ei    = (const int*)d_in[1];
    const int*   batch = (const int*)d_in[2];
    const float* W1    = (const float*)d_in[3];
    const float* b1    = (const float*)d_in[4];
    const float* W2    = (const float*)d_in[5];
    const float* b2    = (const float*)d_in[6];
    float* out = (float*)d_out;

    // Workspace: 4 accumulator arrays x C copies, then dinv/y1/z, gacc, flag.
    const size_t N = N_NODES;
    size_t need8 = (4 * 8 * N + 3 * N + 8 * 3 * N_GRAPHS + 16) * sizeof(float);
    const bool multi = ws_size >= need8;
    const int C = multi ? 8 : 1;

    float* f    = (float*)d_ws;
    float* deg8 = f;
    float* acc1 = deg8 + (size_t)C * N;
    float* accz = acc1 + (size_t)C * N;
    float* acc2 = accz + (size_t)C * N;
    float* dinv = acc2 + (size_t)C * N;
    float* y1   = dinv + N;
    float* z    = y1 + N;
    float* gacc = z + N;
    int*   flag = (int*)(gacc + (size_t)C * 3 * N_GRAPHS);

    const int BS = 256;
    const int nodeGrid = (N_NODES + BS - 1) / BS;
    const int edgeGrid = 2048;
    const int zeroElems = 4 * C * N_NODES + C * 3 * N_GRAPHS;  // contiguous region

    detect_kernel<<<1, 64, 0, stream>>>(ei, flag);
    zero_kernel<<<1024, BS, 0, stream>>>(f, 4 * C * N_NODES);
    zero_kernel<<<1, BS, 0, stream>>>(gacc, C * 3 * N_GRAPHS);
    (void)zeroElems;

    if (multi) {
        deg_kernel<true><<<edgeGrid, BS, 0, stream>>>(ei, flag, deg8);
        dinv_kernel<<<nodeGrid, BS, 0, stream>>>(deg8, C, dinv);
        edge1_kernel<true><<<edgeGrid, BS, 0, stream>>>(ei, flag, x, dinv, acc1, accz);
        node1_kernel<<<nodeGrid, BS, 0, stream>>>(x, dinv, acc1, accz, C, y1, z);
        edge2_kernel<true><<<edgeGrid, BS, 0, stream>>>(ei, flag, dinv, y1, acc2);
        pool_kernel<true><<<nodeGrid, BS, 0, stream>>>(batch, flag, dinv, y1, z, acc2, C, gacc);
    } else {
        deg_kernel<false><<<edgeGrid, BS, 0, stream>>>(ei, flag, deg8);
        dinv_kernel<<<nodeGrid, BS, 0, stream>>>(deg8, C, dinv);
        edge1_kernel<false><<<edgeGrid, BS, 0, stream>>>(ei, flag, x, dinv, acc1, accz);
        node1_kernel<<<nodeGrid, BS, 0, stream>>>(x, dinv, acc1, accz, C, y1, z);
        edge2_kernel<false><<<edgeGrid, BS, 0, stream>>>(ei, flag, dinv, y1, acc2);
        pool_kernel<false><<<nodeGrid, BS, 0, stream>>>(batch, flag, dinv, y1, z, acc2, C, gacc);
    }
    final_kernel<<<1, 64, 0, stream>>>(W1, b1, W2, b2, gacc, C, out);
}